// Round 2
// baseline (290.637 us; speedup 1.0000x reference)
//
#include <hip/hip_runtime.h>
#include <hip/hip_bf16.h>

// ---------------------------------------------------------------------------
// OrthoInitPhasor: fused bf16-MFMA implementation, round 2
//   Algebraic fusion: Kc = x@(Wkm.Wk)^T + (Wkm.bk + bkm)  (same for Q)
//   so the two dependent mod-GEMMs vanish.
//   compose:  Wkk = Wkm@Wk, Wqq = Wqm@Wq (fp32, -> bf16)
//   GEMM_A:   x @ [Wv|Wkk|Wqq]^T + [bv|bkk|bqq] -> VKQ [16384,1536] bf16
//   phasor+chunk-cumsum+LN                      -> nrm [16384,512]  bf16
//   GEMM_O:   nrm @ Wo^T + bo + x               -> out [16384,512]  f32
// ---------------------------------------------------------------------------

typedef __attribute__((ext_vector_type(8))) short short8;   // 8 x bf16 (4 VGPR)
typedef __attribute__((ext_vector_type(4))) float f32x4;

#define M_TOK   16384
#define DIM     512
#define NCHUNK  64

__device__ __forceinline__ void gll16(const void* g, void* l) {
  __builtin_amdgcn_global_load_lds(
      (const __attribute__((address_space(1))) unsigned int*)g,
      (__attribute__((address_space(3))) unsigned int*)l, 16, 0, 0);
}

// --------------------------- f32 -> bf16 convert ---------------------------
__global__ __launch_bounds__(256) void cvt_f32_bf16(
    const float* __restrict__ s, __hip_bfloat16* __restrict__ d, int n4) {
  int i = blockIdx.x * 256 + threadIdx.x;
  if (i >= n4) return;
  float4 v = ((const float4*)s)[i];
  union { __hip_bfloat16 h[4]; uint2 u; } t;
  t.h[0] = __float2bfloat16(v.x);
  t.h[1] = __float2bfloat16(v.y);
  t.h[2] = __float2bfloat16(v.z);
  t.h[3] = __float2bfloat16(v.w);
  ((uint2*)d)[i] = t.u;
}

// ---------------- pack Wv -> Wall rows 0-511, Wo -> rows 1536-2047 ---------
__global__ __launch_bounds__(256) void pack_w2(
    const float* __restrict__ Wv, const float* __restrict__ Wo,
    const float* __restrict__ bv, __hip_bfloat16* __restrict__ Wall,
    float* __restrict__ bc1) {
  int t = blockIdx.x * 256 + threadIdx.x;   // 131072 threads
  int m = t >> 16;                          // 0: Wv, 1: Wo
  int r = (t & 65535) * 4;
  const float* src = m ? Wo : Wv;
  __hip_bfloat16* dst = Wall + (m ? (size_t)1536 * 512 : 0);
  float4 v = *(const float4*)(src + r);
  union { __hip_bfloat16 h[4]; uint2 u; } o;
  o.h[0] = __float2bfloat16(v.x);
  o.h[1] = __float2bfloat16(v.y);
  o.h[2] = __float2bfloat16(v.z);
  o.h[3] = __float2bfloat16(v.w);
  ((uint2*)dst)[r >> 2] = o.u;
  if (t < 512) bc1[t] = bv[t];
}

// ---------------- compose Wkk = Wkm@Wk, Wqq = Wqm@Wq (fp32 -> bf16) --------
// grid (16,16,2), block 256. Writes Wall rows 512-1023 (z=0), 1024-1535 (z=1)
__global__ __launch_bounds__(256) void compose_w(
    const float* __restrict__ Wkm, const float* __restrict__ Wk,
    const float* __restrict__ Wqm, const float* __restrict__ Wq,
    __hip_bfloat16* __restrict__ Wall) {
  const float* Am = blockIdx.z ? Wqm : Wkm;
  const float* Bm = blockIdx.z ? Wq : Wk;
  __hip_bfloat16* C = Wall + (size_t)(512 + blockIdx.z * 512) * 512;
  __shared__ float As[32][33];
  __shared__ float Bs[32][33];
  const int tid = threadIdx.x;
  const int tx = tid & 31, ty = tid >> 5;   // ty 0..7
  const int bi = blockIdx.y * 32, bj = blockIdx.x * 32;
  float acc[4] = {0.f, 0.f, 0.f, 0.f};
  for (int kt = 0; kt < 512; kt += 32) {
#pragma unroll
    for (int l = tid; l < 1024; l += 256) {
      int r = l >> 5, c = l & 31;
      As[r][c] = Am[(size_t)(bi + r) * 512 + kt + c];
      Bs[r][c] = Bm[(size_t)(kt + r) * 512 + bj + c];
    }
    __syncthreads();
#pragma unroll 8
    for (int k = 0; k < 32; k++) {
      float b = Bs[k][tx];
#pragma unroll
      for (int rr = 0; rr < 4; rr++) acc[rr] += As[ty + rr * 8][k] * b;
    }
    __syncthreads();
  }
#pragma unroll
  for (int rr = 0; rr < 4; rr++)
    C[(size_t)(bi + ty + rr * 8) * 512 + bj + tx] = __float2bfloat16(acc[rr]);
}

// ---------------- compose bias: bc1[512+z*512+i] = Wm[i,:].b0 + bm[i] ------
__global__ __launch_bounds__(512) void compose_b(
    const float* __restrict__ Wkm, const float* __restrict__ bk,
    const float* __restrict__ bkm, const float* __restrict__ Wqm,
    const float* __restrict__ bq, const float* __restrict__ bqm,
    float* __restrict__ bc1) {
  const int z = blockIdx.x;
  const int i = threadIdx.x;
  const float* Wm = z ? Wqm : Wkm;
  const float* b0 = z ? bq : bk;
  const float* bm = z ? bqm : bkm;
  float acc = bm[i];
  const float4* w4 = (const float4*)(Wm + (size_t)i * 512);
  const float4* b4 = (const float4*)b0;
  for (int k = 0; k < 128; k++) {
    float4 w = w4[k];
    float4 bb = b4[k];
    acc += w.x * bb.x + w.y * bb.y + w.z * bb.z + w.w * bb.w;
  }
  bc1[512 + z * 512 + i] = acc;
}

// ------------------------------- GEMM (B^T) --------------------------------
// C[m,n] = sum_k A[m,k] * Bt[n,k] + bias[n]   (+ resid[m,n] for EPI==1)
template <int EPI>
__global__ __launch_bounds__(256) void gemm_bt(
    const __hip_bfloat16* __restrict__ A, int lda,
    const __hip_bfloat16* __restrict__ Bt,
    const float* __restrict__ bias,
    void* __restrict__ Cout, int ldc,
    const float* __restrict__ resid) {
  constexpr int K = 512, BK = 32;
  __shared__ __align__(16) __hip_bfloat16 As[128 * BK];
  __shared__ __align__(16) __hip_bfloat16 Bs[128 * BK];

  const int tid  = threadIdx.x;
  const int lane = tid & 63;
  const int w    = tid >> 6;        // wave 0..3
  const int wm   = w >> 1;          // wave row (0..1)
  const int wn   = w & 1;           // wave col (0..1)
  const int m0   = blockIdx.y * 128;
  const int n0   = blockIdx.x * 128;

  const int rS0    = (w * 2 + 0) * 16 + (lane >> 2);
  const int rS1    = (w * 2 + 1) * 16 + (lane >> 2);
  const int kInRow = (lane & 3) * 8;
  const __hip_bfloat16* gA0 = A + (size_t)(m0 + rS0) * lda + kInRow;
  const __hip_bfloat16* gA1 = A + (size_t)(m0 + rS1) * lda + kInRow;
  const __hip_bfloat16* gB0 = Bt + (size_t)(n0 + rS0) * K + kInRow;
  const __hip_bfloat16* gB1 = Bt + (size_t)(n0 + rS1) * K + kInRow;
  char* ldsA0 = (char*)As + (w * 2 + 0) * 1024;
  char* ldsA1 = (char*)As + (w * 2 + 1) * 1024;
  char* ldsB0 = (char*)Bs + (w * 2 + 0) * 1024;
  char* ldsB1 = (char*)Bs + (w * 2 + 1) * 1024;

  f32x4 acc[4][4] = {};

  const int rfA = lane & 15;        // fragment row within 16-tile
  const int rfK = (lane >> 4) * 8;  // fragment k offset

  for (int kt = 0; kt < K; kt += BK) {
    __syncthreads();
    gll16(gA0 + kt, ldsA0);
    gll16(gA1 + kt, ldsA1);
    gll16(gB0 + kt, ldsB0);
    gll16(gB1 + kt, ldsB1);
    __syncthreads();

    short8 af[4], bf[4];
#pragma unroll
    for (int i = 0; i < 4; i++)
      af[i] = *(const short8*)(As + (wm * 64 + i * 16 + rfA) * BK + rfK);
#pragma unroll
    for (int j = 0; j < 4; j++)
      bf[j] = *(const short8*)(Bs + (wn * 64 + j * 16 + rfA) * BK + rfK);
#pragma unroll
    for (int i = 0; i < 4; i++)
#pragma unroll
      for (int j = 0; j < 4; j++)
        acc[i][j] = __builtin_amdgcn_mfma_f32_16x16x32_bf16(
            af[i], bf[j], acc[i][j], 0, 0, 0);
  }

  // epilogue: C/D layout col = lane&15, row = (lane>>4)*4 + reg
  const int cq = lane >> 4;
#pragma unroll
  for (int i = 0; i < 4; i++) {
    int row = m0 + wm * 64 + i * 16 + cq * 4;
#pragma unroll
    for (int j = 0; j < 4; j++) {
      int col = n0 + wn * 64 + j * 16 + (lane & 15);
      float bz = bias[col];
#pragma unroll
      for (int r = 0; r < 4; r++) {
        float v = acc[i][j][r] + bz;
        size_t o = (size_t)(row + r) * ldc + col;
        if (EPI == 0) {
          ((__hip_bfloat16*)Cout)[o] = __float2bfloat16(v);
        } else {
          ((float*)Cout)[o] = v + resid[o];
        }
      }
    }
  }
}

// ------------------- phasor + chunk cumsum + LayerNorm ---------------------
// grid: 256 blocks (= B*nC), 512 threads (one per column d)
// VKQ layout: V at col 0, Kc at col 512, Qc at col 1024
__global__ __launch_bounds__(512) void phase_cumsum_ln(
    const __hip_bfloat16* __restrict__ VKQ,    // [16384,1536]
    const float* __restrict__ bp,              // [4096,512]
    const float* __restrict__ mod_scale,       // [1]
    const float* __restrict__ ln_g, const float* __restrict__ ln_b,
    __hip_bfloat16* __restrict__ normed) {
  __shared__ __hip_bfloat16 R[64 * 512];       // 64 KB: retrieved (bf16)
  const int d      = threadIdx.x;              // 0..511
  const int blk    = blockIdx.x;               // 0..255
  const int token0 = blk * 64;
  const int sg0    = (blk & (NCHUNK - 1)) * 64;  // base_phases row base
  const float msc  = mod_scale[0];
  const float inv_sqrt_d = 0.044194173824159216f;  // 1/sqrt(512)

  float mr = 0.f, mi = 0.f;
  for (int s = 0; s < 64; ++s) {
    size_t t = (size_t)(token0 + s);
    float v  = __bfloat162float(VKQ[t * 1536 + d]);
    float km = __bfloat162float(VKQ[t * 1536 + 512 + d]);
    float qm = __bfloat162float(VKQ[t * 1536 + 1024 + d]);
    float b  = bp[(size_t)(sg0 + s) * 512 + d];
    float kp = b + km * msc;
    float qp = b + qm * msc;
    float sk, ck, sq, cq;
    __sincosf(kp, &sk, &ck);
    __sincosf(qp, &sq, &cq);
    mr += v * ck;
    mi += v * sk;
    R[s * 512 + d] = __float2bfloat16((mr * cq + mi * sq) * inv_sqrt_d);
  }
  __syncthreads();

  const int lane = threadIdx.x & 63;
  const int wv   = threadIdx.x >> 6;  // wave 0..7, owns rows wv*8 .. wv*8+7
  float gj[8], bj[8];
#pragma unroll
  for (int j = 0; j < 8; j++) {
    int col = lane + 64 * j;
    gj[j] = ln_g[col];
    bj[j] = ln_b[col];
  }
  for (int rr = 0; rr < 8; ++rr) {
    int row = wv * 8 + rr;
    float vals[8], sum = 0.f, sq2 = 0.f;
#pragma unroll
    for (int j = 0; j < 8; j++) {
      float x = __bfloat162float(R[row * 512 + lane + 64 * j]);
      vals[j] = x;
      sum += x;
      sq2 += x * x;
    }
#pragma unroll
    for (int off = 32; off; off >>= 1) {
      sum += __shfl_xor(sum, off, 64);
      sq2 += __shfl_xor(sq2, off, 64);
    }
    float mu   = sum * (1.f / 512.f);
    float var  = sq2 * (1.f / 512.f) - mu * mu;
    float rstd = rsqrtf(var + 1e-5f);
    size_t base = (size_t)(token0 + row) * 512;
#pragma unroll
    for (int j = 0; j < 8; j++) {
      int col = lane + 64 * j;
      float nv = (vals[j] - mu) * rstd * gj[j] + bj[j];
      normed[base + col] = __float2bfloat16(nv);
    }
  }
}

// ------------------------------- launcher ----------------------------------
extern "C" void kernel_launch(void* const* d_in, const int* in_sizes, int n_in,
                              void* d_out, int out_size, void* d_ws,
                              size_t ws_size, hipStream_t stream) {
  const float* x    = (const float*)d_in[0];
  const float* bp   = (const float*)d_in[1];
  const float* Wk   = (const float*)d_in[2];
  const float* bk   = (const float*)d_in[3];
  const float* Wv   = (const float*)d_in[4];
  const float* bv   = (const float*)d_in[5];
  const float* Wq   = (const float*)d_in[6];
  const float* bq   = (const float*)d_in[7];
  const float* Wkm  = (const float*)d_in[8];
  const float* bkm  = (const float*)d_in[9];
  const float* Wqm  = (const float*)d_in[10];
  const float* bqm  = (const float*)d_in[11];
  const float* msc  = (const float*)d_in[12];
  const float* lng  = (const float*)d_in[13];
  const float* lnb  = (const float*)d_in[14];
  const float* Wo   = (const float*)d_in[15];
  const float* bo   = (const float*)d_in[16];
  float* out = (float*)d_out;

  char* ws = (char*)d_ws;
  __hip_bfloat16* x_bf = (__hip_bfloat16*)ws;  ws += (size_t)M_TOK * DIM * 2;
  __hip_bfloat16* Wall = (__hip_bfloat16*)ws;  ws += (size_t)2048 * 512 * 2;
  float*          bc1  = (float*)ws;           ws += 1536 * 4;
  __hip_bfloat16* VKQ  = (__hip_bfloat16*)ws;  ws += (size_t)M_TOK * 1536 * 2;
  __hip_bfloat16* nrm  = (__hip_bfloat16*)ws;  ws += (size_t)M_TOK * DIM * 2;

  // 1) convert x to bf16
  cvt_f32_bf16<<<8192, 256, 0, stream>>>(x, x_bf, 2097152);
  // 2) pack Wv, Wo + bv
  pack_w2<<<512, 256, 0, stream>>>(Wv, Wo, bv, Wall, bc1);
  // 3) compose Wkk = Wkm@Wk, Wqq = Wqm@Wq  (fp32 -> bf16 into Wall)
  compose_w<<<dim3(16, 16, 2), 256, 0, stream>>>(Wkm, Wk, Wqm, Wq, Wall);
  // 4) compose biases bkk = Wkm@bk + bkm, bqq = Wqm@bq + bqm
  compose_b<<<2, 512, 0, stream>>>(Wkm, bk, bkm, Wqm, bq, bqm, bc1);
  // 5) VKQ = x @ [Wv|Wkk|Wqq]^T + [bv|bkk|bqq]    (M=16384, N=1536)
  gemm_bt<0><<<dim3(12, 128), 256, 0, stream>>>(x_bf, DIM, Wall, bc1, VKQ,
                                                1536, nullptr);
  // 6) phasor + chunked cumsum + LayerNorm -> normed (bf16)
  phase_cumsum_ln<<<256, 512, 0, stream>>>(VKQ, bp, msc, lng, lnb, nrm);
  // 7) out = x + normed @ Wo^T + bo   (f32)
  gemm_bt<1><<<dim3(4, 128), 256, 0, stream>>>(nrm, DIM,
                                               Wall + (size_t)1536 * 512, bo,
                                               out, DIM, x);
}

// Round 3
// 211.915 us; speedup vs baseline: 1.3715x; 1.3715x over previous
//
#include <hip/hip_runtime.h>
#include <hip/hip_bf16.h>

// ---------------------------------------------------------------------------
// OrthoInitPhasor round 3
//   Algebraic fusion: Kc = x@(Wkm.Wk)^T + (Wkm.bk+bkm); same for Q.
//   prep:         pack Wv/Wo -> bf16, cvt Wkm/Wqm -> bf16, transpose-cvt
//                 Wk/Wq -> bf16, compose biases (wave-per-row)
//   gemm_compose: Wkk = Wkm@Wk, Wqq = Wqm@Wq via MFMA (A=Wkm, Bt=Wk^T)
//   GEMM_A:       x @ [Wv|Wkk|Wqq]^T + bias -> VKQ [16384,1536] bf16
//   phasor+chunk-cumsum+LN                  -> nrm [16384,512]  bf16
//   GEMM_O:       nrm @ Wo^T + bo + x       -> out [16384,512]  f32
// ---------------------------------------------------------------------------

typedef __attribute__((ext_vector_type(8))) short short8;   // 8 x bf16
typedef __attribute__((ext_vector_type(4))) float f32x4;

#define M_TOK   16384
#define DIM     512
#define NCHUNK  64

__device__ __forceinline__ void gll16(const void* g, void* l) {
  __builtin_amdgcn_global_load_lds(
      (const __attribute__((address_space(1))) unsigned int*)g,
      (__attribute__((address_space(3))) unsigned int*)l, 16, 0, 0);
}

__device__ __forceinline__ uint2 pack4bf(float4 v) {
  union { __hip_bfloat16 h[4]; uint2 u; } t;
  t.h[0] = __float2bfloat16(v.x);
  t.h[1] = __float2bfloat16(v.y);
  t.h[2] = __float2bfloat16(v.z);
  t.h[3] = __float2bfloat16(v.w);
  return t.u;
}

// --------------------------- f32 -> bf16 convert ---------------------------
__global__ __launch_bounds__(256) void cvt_f32_bf16(
    const float* __restrict__ s, __hip_bfloat16* __restrict__ d, int n4) {
  int i = blockIdx.x * 256 + threadIdx.x;
  if (i >= n4) return;
  ((uint2*)d)[i] = pack4bf(((const float4*)s)[i]);
}

// ------------------------------ prep (merged) ------------------------------
// blocks 0..511    : pack Wv -> Wall[0:512), Wo -> Wall[1536:2048); bv -> bc1
// blocks 512..1023 : cvt Wkm/Wqm -> Wm_bf (z*262144)
// blocks 1024..1151: transpose-cvt Wk/Wq -> WT_bf (z*262144), 64x64 tiles
// blocks 1152..1407: compose biases (wave per row): bc1[512+z*512+i]
__global__ __launch_bounds__(256) void prep(
    const float* __restrict__ Wv, const float* __restrict__ Wo,
    const float* __restrict__ bv,
    const float* __restrict__ Wkm, const float* __restrict__ Wqm,
    const float* __restrict__ Wk, const float* __restrict__ Wq,
    const float* __restrict__ bk, const float* __restrict__ bkm,
    const float* __restrict__ bq, const float* __restrict__ bqm,
    __hip_bfloat16* __restrict__ Wall, float* __restrict__ bc1,
    __hip_bfloat16* __restrict__ Wm_bf, __hip_bfloat16* __restrict__ WT_bf) {
  const int b = blockIdx.x;
  const int tid = threadIdx.x;
  if (b < 512) {
    int m = b >> 8;
    int idx = ((b & 255) * 256 + tid) * 4;
    const float* src = m ? Wo : Wv;
    __hip_bfloat16* dst = Wall + (m ? (size_t)1536 * 512 : 0);
    ((uint2*)dst)[idx >> 2] = pack4bf(*(const float4*)(src + idx));
    int t = b * 256 + tid;
    if (t < 512) bc1[t] = bv[t];
  } else if (b < 1024) {
    int bb = b - 512;
    int m = bb >> 8;
    int idx = ((bb & 255) * 256 + tid) * 4;
    const float* src = m ? Wqm : Wkm;
    ((uint2*)(Wm_bf + (size_t)m * 262144))[idx >> 2] =
        pack4bf(*(const float4*)(src + idx));
  } else if (b < 1152) {
    __shared__ float tile[64][65];
    int bb = b - 1024;
    int z = bb >> 6;
    int tl = bb & 63;
    int tr = tl >> 3, tc = tl & 7;          // 64x64 tile (tr,tc)
    const float* src = z ? Wq : Wk;
#pragma unroll
    for (int i = 0; i < 4; i++) {
      int r = (tid >> 4) + 16 * i;
      int c4 = (tid & 15) * 4;
      float4 v = *(const float4*)(src + (size_t)(tr * 64 + r) * 512 +
                                  tc * 64 + c4);
      tile[r][c4 + 0] = v.x;
      tile[r][c4 + 1] = v.y;
      tile[r][c4 + 2] = v.z;
      tile[r][c4 + 3] = v.w;
    }
    __syncthreads();
    int orow = tid >> 2;                    // output row = input col
    int seg = tid & 3;                      // 16 elems per seg
    __hip_bfloat16* dst = WT_bf + (size_t)z * 262144 +
                          (size_t)(tc * 64 + orow) * 512 + tr * 64 + seg * 16;
#pragma unroll
    for (int q = 0; q < 4; q++) {
      float4 v;
      v.x = tile[seg * 16 + q * 4 + 0][orow];
      v.y = tile[seg * 16 + q * 4 + 1][orow];
      v.z = tile[seg * 16 + q * 4 + 2][orow];
      v.w = tile[seg * 16 + q * 4 + 3][orow];
      *(uint2*)(dst + q * 4) = pack4bf(v);
    }
  } else {
    int row = (b - 1152) * 4 + (tid >> 6);  // 0..1023
    int lane = tid & 63;
    int z = row >> 9;
    int i = row & 511;
    const float* Wm = z ? Wqm : Wkm;
    const float* b0 = z ? bq : bk;
    const float* bm = z ? bqm : bkm;
    const float4* w4 = (const float4*)(Wm + (size_t)i * 512 + lane * 8);
    const float4* v4 = (const float4*)(b0 + lane * 8);
    float4 w0 = w4[0], w1 = w4[1], c0 = v4[0], c1 = v4[1];
    float acc = w0.x * c0.x + w0.y * c0.y + w0.z * c0.z + w0.w * c0.w +
                w1.x * c1.x + w1.y * c1.y + w1.z * c1.z + w1.w * c1.w;
#pragma unroll
    for (int off = 32; off; off >>= 1) acc += __shfl_xor(acc, off, 64);
    if (lane == 0) bc1[512 + z * 512 + i] = acc + bm[i];
  }
}

// ------------------------------- GEMM (B^T) --------------------------------
// C[m,n] = sum_k A[m,k] * Bt[n,k] + bias[n]   (+ resid[m,n] for EPI==1)
template <int EPI>
__global__ __launch_bounds__(256) void gemm_bt(
    const __hip_bfloat16* __restrict__ A, int lda,
    const __hip_bfloat16* __restrict__ Bt,
    const float* __restrict__ bias,
    void* __restrict__ Cout, int ldc,
    const float* __restrict__ resid) {
  constexpr int K = 512, BK = 32;
  __shared__ __align__(16) __hip_bfloat16 As[128 * BK];
  __shared__ __align__(16) __hip_bfloat16 Bs[128 * BK];

  const int tid  = threadIdx.x;
  const int lane = tid & 63;
  const int w    = tid >> 6;
  const int wm   = w >> 1;
  const int wn   = w & 1;
  const int m0   = blockIdx.y * 128;
  const int n0   = blockIdx.x * 128;

  const int rS0    = (w * 2 + 0) * 16 + (lane >> 2);
  const int rS1    = (w * 2 + 1) * 16 + (lane >> 2);
  const int kInRow = (lane & 3) * 8;
  const __hip_bfloat16* gA0 = A + (size_t)(m0 + rS0) * lda + kInRow;
  const __hip_bfloat16* gA1 = A + (size_t)(m0 + rS1) * lda + kInRow;
  const __hip_bfloat16* gB0 = Bt + (size_t)(n0 + rS0) * K + kInRow;
  const __hip_bfloat16* gB1 = Bt + (size_t)(n0 + rS1) * K + kInRow;
  char* ldsA0 = (char*)As + (w * 2 + 0) * 1024;
  char* ldsA1 = (char*)As + (w * 2 + 1) * 1024;
  char* ldsB0 = (char*)Bs + (w * 2 + 0) * 1024;
  char* ldsB1 = (char*)Bs + (w * 2 + 1) * 1024;

  f32x4 acc[4][4] = {};

  const int rfA = lane & 15;
  const int rfK = (lane >> 4) * 8;

  for (int kt = 0; kt < K; kt += BK) {
    __syncthreads();
    gll16(gA0 + kt, ldsA0);
    gll16(gA1 + kt, ldsA1);
    gll16(gB0 + kt, ldsB0);
    gll16(gB1 + kt, ldsB1);
    __syncthreads();

    short8 af[4], bf[4];
#pragma unroll
    for (int i = 0; i < 4; i++)
      af[i] = *(const short8*)(As + (wm * 64 + i * 16 + rfA) * BK + rfK);
#pragma unroll
    for (int j = 0; j < 4; j++)
      bf[j] = *(const short8*)(Bs + (wn * 64 + j * 16 + rfA) * BK + rfK);
#pragma unroll
    for (int i = 0; i < 4; i++)
#pragma unroll
      for (int j = 0; j < 4; j++)
        acc[i][j] = __builtin_amdgcn_mfma_f32_16x16x32_bf16(
            af[i], bf[j], acc[i][j], 0, 0, 0);
  }

  const int cq = lane >> 4;
#pragma unroll
  for (int i = 0; i < 4; i++) {
    int row = m0 + wm * 64 + i * 16 + cq * 4;
#pragma unroll
    for (int j = 0; j < 4; j++) {
      int col = n0 + wn * 64 + j * 16 + (lane & 15);
      float bz = bias[col];
#pragma unroll
      for (int r = 0; r < 4; r++) {
        float v = acc[i][j][r] + bz;
        size_t o = (size_t)(row + r) * ldc + col;
        if (EPI == 0) {
          ((__hip_bfloat16*)Cout)[o] = __float2bfloat16(v);
        } else {
          ((float*)Cout)[o] = v + resid[o];
        }
      }
    }
  }
}

// --------------- compose GEMM: Wkk=Wkm@Wk, Wqq=Wqm@Wq (MFMA) ---------------
// grid (4,4,2): C[i,j] = sum_t A[i,t]*Bt[j,t], A=Wm_bf+z*256K, Bt=WT_bf+z*256K
__global__ __launch_bounds__(256) void gemm_compose(
    const __hip_bfloat16* __restrict__ Wm_bf,
    const __hip_bfloat16* __restrict__ WT_bf,
    __hip_bfloat16* __restrict__ Wall) {
  constexpr int K = 512, BK = 32;
  const __hip_bfloat16* A  = Wm_bf + (size_t)blockIdx.z * 262144;
  const __hip_bfloat16* Bt = WT_bf + (size_t)blockIdx.z * 262144;
  __hip_bfloat16* C = Wall + (size_t)(512 + blockIdx.z * 512) * 512;
  __shared__ __align__(16) __hip_bfloat16 As[128 * BK];
  __shared__ __align__(16) __hip_bfloat16 Bs[128 * BK];

  const int tid  = threadIdx.x;
  const int lane = tid & 63;
  const int w    = tid >> 6;
  const int wm   = w >> 1;
  const int wn   = w & 1;
  const int m0   = blockIdx.y * 128;
  const int n0   = blockIdx.x * 128;

  const int rS0    = (w * 2 + 0) * 16 + (lane >> 2);
  const int rS1    = (w * 2 + 1) * 16 + (lane >> 2);
  const int kInRow = (lane & 3) * 8;
  const __hip_bfloat16* gA0 = A + (size_t)(m0 + rS0) * K + kInRow;
  const __hip_bfloat16* gA1 = A + (size_t)(m0 + rS1) * K + kInRow;
  const __hip_bfloat16* gB0 = Bt + (size_t)(n0 + rS0) * K + kInRow;
  const __hip_bfloat16* gB1 = Bt + (size_t)(n0 + rS1) * K + kInRow;
  char* ldsA0 = (char*)As + (w * 2 + 0) * 1024;
  char* ldsA1 = (char*)As + (w * 2 + 1) * 1024;
  char* ldsB0 = (char*)Bs + (w * 2 + 0) * 1024;
  char* ldsB1 = (char*)Bs + (w * 2 + 1) * 1024;

  f32x4 acc[4][4] = {};
  const int rfA = lane & 15;
  const int rfK = (lane >> 4) * 8;

  for (int kt = 0; kt < K; kt += BK) {
    __syncthreads();
    gll16(gA0 + kt, ldsA0);
    gll16(gA1 + kt, ldsA1);
    gll16(gB0 + kt, ldsB0);
    gll16(gB1 + kt, ldsB1);
    __syncthreads();

    short8 af[4], bf[4];
#pragma unroll
    for (int i = 0; i < 4; i++)
      af[i] = *(const short8*)(As + (wm * 64 + i * 16 + rfA) * BK + rfK);
#pragma unroll
    for (int j = 0; j < 4; j++)
      bf[j] = *(const short8*)(Bs + (wn * 64 + j * 16 + rfA) * BK + rfK);
#pragma unroll
    for (int i = 0; i < 4; i++)
#pragma unroll
      for (int j = 0; j < 4; j++)
        acc[i][j] = __builtin_amdgcn_mfma_f32_16x16x32_bf16(
            af[i], bf[j], acc[i][j], 0, 0, 0);
  }

  const int cq = lane >> 4;
#pragma unroll
  for (int i = 0; i < 4; i++) {
    int row = m0 + wm * 64 + i * 16 + cq * 4;
#pragma unroll
    for (int j = 0; j < 4; j++) {
      int col = n0 + wn * 64 + j * 16 + (lane & 15);
#pragma unroll
      for (int r = 0; r < 4; r++)
        C[(size_t)(row + r) * 512 + col] = __float2bfloat16(acc[i][j][r]);
    }
  }
}

// ------------------- phasor + chunk cumsum + LayerNorm ---------------------
__global__ __launch_bounds__(512) void phase_cumsum_ln(
    const __hip_bfloat16* __restrict__ VKQ,    // [16384,1536]
    const float* __restrict__ bp,              // [4096,512]
    const float* __restrict__ mod_scale,
    const float* __restrict__ ln_g, const float* __restrict__ ln_b,
    __hip_bfloat16* __restrict__ normed) {
  __shared__ __hip_bfloat16 R[64 * 512];
  const int d      = threadIdx.x;
  const int blk    = blockIdx.x;
  const int token0 = blk * 64;
  const int sg0    = (blk & (NCHUNK - 1)) * 64;
  const float msc  = mod_scale[0];
  const float inv_sqrt_d = 0.044194173824159216f;

  float mr = 0.f, mi = 0.f;
  for (int s = 0; s < 64; ++s) {
    size_t t = (size_t)(token0 + s);
    float v  = __bfloat162float(VKQ[t * 1536 + d]);
    float km = __bfloat162float(VKQ[t * 1536 + 512 + d]);
    float qm = __bfloat162float(VKQ[t * 1536 + 1024 + d]);
    float b  = bp[(size_t)(sg0 + s) * 512 + d];
    float kp = b + km * msc;
    float qp = b + qm * msc;
    float sk, ck, sq, cq;
    __sincosf(kp, &sk, &ck);
    __sincosf(qp, &sq, &cq);
    mr += v * ck;
    mi += v * sk;
    R[s * 512 + d] = __float2bfloat16((mr * cq + mi * sq) * inv_sqrt_d);
  }
  __syncthreads();

  const int lane = threadIdx.x & 63;
  const int wv   = threadIdx.x >> 6;
  float gj[8], bj[8];
#pragma unroll
  for (int j = 0; j < 8; j++) {
    int col = lane + 64 * j;
    gj[j] = ln_g[col];
    bj[j] = ln_b[col];
  }
  for (int rr = 0; rr < 8; ++rr) {
    int row = wv * 8 + rr;
    float vals[8], sum = 0.f, sq2 = 0.f;
#pragma unroll
    for (int j = 0; j < 8; j++) {
      float x = __bfloat162float(R[row * 512 + lane + 64 * j]);
      vals[j] = x;
      sum += x;
      sq2 += x * x;
    }
#pragma unroll
    for (int off = 32; off; off >>= 1) {
      sum += __shfl_xor(sum, off, 64);
      sq2 += __shfl_xor(sq2, off, 64);
    }
    float mu   = sum * (1.f / 512.f);
    float var  = sq2 * (1.f / 512.f) - mu * mu;
    float rstd = rsqrtf(var + 1e-5f);
    size_t base = (size_t)(token0 + row) * 512;
#pragma unroll
    for (int j = 0; j < 8; j++) {
      int col = lane + 64 * j;
      float nv = (vals[j] - mu) * rstd * gj[j] + bj[j];
      normed[base + col] = __float2bfloat16(nv);
    }
  }
}

// ------------------------------- launcher ----------------------------------
extern "C" void kernel_launch(void* const* d_in, const int* in_sizes, int n_in,
                              void* d_out, int out_size, void* d_ws,
                              size_t ws_size, hipStream_t stream) {
  const float* x    = (const float*)d_in[0];
  const float* bp   = (const float*)d_in[1];
  const float* Wk   = (const float*)d_in[2];
  const float* bk   = (const float*)d_in[3];
  const float* Wv   = (const float*)d_in[4];
  const float* bv   = (const float*)d_in[5];
  const float* Wq   = (const float*)d_in[6];
  const float* bq   = (const float*)d_in[7];
  const float* Wkm  = (const float*)d_in[8];
  const float* bkm  = (const float*)d_in[9];
  const float* Wqm  = (const float*)d_in[10];
  const float* bqm  = (const float*)d_in[11];
  const float* msc  = (const float*)d_in[12];
  const float* lng  = (const float*)d_in[13];
  const float* lnb  = (const float*)d_in[14];
  const float* Wo   = (const float*)d_in[15];
  const float* bo   = (const float*)d_in[16];
  float* out = (float*)d_out;

  char* ws = (char*)d_ws;
  __hip_bfloat16* x_bf  = (__hip_bfloat16*)ws;  ws += (size_t)M_TOK * DIM * 2;
  __hip_bfloat16* Wall  = (__hip_bfloat16*)ws;  ws += (size_t)2048 * 512 * 2;
  __hip_bfloat16* Wm_bf = (__hip_bfloat16*)ws;  ws += (size_t)2 * 262144 * 2;
  __hip_bfloat16* WT_bf = (__hip_bfloat16*)ws;  ws += (size_t)2 * 262144 * 2;
  float*          bc1   = (float*)ws;           ws += 1536 * 4;
  __hip_bfloat16* VKQ   = (__hip_bfloat16*)ws;  ws += (size_t)M_TOK * 1536 * 2;
  __hip_bfloat16* nrm   = (__hip_bfloat16*)ws;  ws += (size_t)M_TOK * DIM * 2;

  // 1) convert x to bf16
  cvt_f32_bf16<<<8192, 256, 0, stream>>>(x, x_bf, 2097152);
  // 2) merged prep: pack/cvt/transpose weights + compose biases
  prep<<<1408, 256, 0, stream>>>(Wv, Wo, bv, Wkm, Wqm, Wk, Wq, bk, bkm, bq,
                                 bqm, Wall, bc1, Wm_bf, WT_bf);
  // 3) MFMA compose: Wkk, Wqq -> Wall rows 512..1535
  gemm_compose<<<dim3(4, 4, 2), 256, 0, stream>>>(Wm_bf, WT_bf, Wall);
  // 4) VKQ = x @ [Wv|Wkk|Wqq]^T + [bv|bkk|bqq]
  gemm_bt<0><<<dim3(12, 128), 256, 0, stream>>>(x_bf, DIM, Wall, bc1, VKQ,
                                                1536, nullptr);
  // 5) phasor + chunked cumsum + LayerNorm -> normed (bf16)
  phase_cumsum_ln<<<256, 512, 0, stream>>>(VKQ, bp, msc, lng, lnb, nrm);
  // 6) out = x + normed @ Wo^T + bo
  gemm_bt<1><<<dim3(4, 128), 256, 0, stream>>>(nrm, DIM,
                                               Wall + (size_t)1536 * 512, bo,
                                               out, DIM, x);
}